// Round 15
// baseline (138.257 us; speedup 1.0000x reference)
//
#include <hip/hip_runtime.h>
#include <hip/hip_bf16.h>

// ConvSelfAttn: B=8, N=4096, C=64, d=8. FP32 I/O.
// R15 = R14 + __launch_bounds__(256,5) on attn. R14's register-direct PV
// dropped VGPR to 44; (256,4) was pinning the scheduler at 4 blocks/CU.
// 5 blocks/CU (cap 51 >= 44, LDS 12.8KB x 5 = 64KB) = free +25% occupancy.
// Everything else identical to R14.

#define BB 8
#define NN 4096
#define CC 64
#define PSTRIDE 72
#define LOG2E 1.44269504088896f

typedef _Float16 f16;
typedef _Float16 half8 __attribute__((ext_vector_type(8)));
typedef _Float16 half4 __attribute__((ext_vector_type(4)));
typedef __fp16 fp16x2 __attribute__((ext_vector_type(2)));
typedef float floatx4 __attribute__((ext_vector_type(4)));

static __device__ inline half4 pack4(float a, float b, float c, float d) {
    fp16x2 lo = __builtin_amdgcn_cvt_pkrtz(a, b);
    fp16x2 hi = __builtin_amdgcn_cvt_pkrtz(c, d);
    unsigned int lou = __builtin_bit_cast(unsigned int, lo);
    unsigned int hiu = __builtin_bit_cast(unsigned int, hi);
    unsigned long long packed = (unsigned long long)lou | ((unsigned long long)hiu << 32);
    return __builtin_bit_cast(half4, packed);
}

// ws layouts (halfs):
//   Qh [B*N][8]                     Q pre-scaled by log2e
//   Kf [B][128 pair][64 lane][8]    pair-interleaved S A-frags (16x16x16);
//                                   quad2 = {1,0,0,0} mf channel, quad3 = 0
//   Vf [B][128 pair][4 ct][64 lane][8]  pair-interleaved PV A-frags
//                                   (16x16x16): halfs 0-3 = even 16-key tile
//                                   (A[m=ch=n16][k=key=quad*4+j]), 4-7 = odd
//   qn2 [B*N] f32 | kn2 [B*N] f32 | Mk2 [B] f32

// ---------------- fused projection + fragment repack + norms ----------------
// grid 512 x 256 (4 waves x 16 pixels; block = 64 pixels of one batch)
__global__ __launch_bounds__(256) void proj_all_kernel(
    const float* __restrict__ x,
    const float* __restrict__ wq, const float* __restrict__ bq,
    const float* __restrict__ wk, const float* __restrict__ bk,
    const float* __restrict__ wv, const float* __restrict__ bv,
    f16* __restrict__ Qh, f16* __restrict__ Kf, f16* __restrict__ Vf,
    float* __restrict__ qn2, float* __restrict__ kn2)
{
    __shared__ alignas(16) f16 Ws[80][PSTRIDE];  // rows 0-63=V, 64-71=Q, 72-79=K
    __shared__ float Bs[80];
    __shared__ alignas(16) f16 Vs[64][68];       // [pixel][ch], pitch 68
    __shared__ alignas(16) f16 Ks[64][12];       // [pixel][ch]
    const int tid = threadIdx.x;

    for (int i = tid; i < 4096; i += 256) {
        int cin = i >> 6, cout = i & 63;
        Ws[cout][cin] = (f16)wv[i];
    }
    for (int i = tid; i < 512; i += 256) {
        int cin = i >> 3, c = i & 7;
        Ws[64 + c][cin] = (f16)(wq[i] * LOG2E);
        Ws[72 + c][cin] = (f16)wk[i];
    }
    if (tid < 80)
        Bs[tid] = (tid < 64) ? bv[tid]
                : (tid < 72 ? bq[tid - 64] * LOG2E : bk[tid - 72]);
    __syncthreads();

    const int wave = tid >> 6, lane = tid & 63;
    const int quad = lane >> 4, n16 = lane & 15;
    const long pb = (long)blockIdx.x * 64;
    const long p0 = pb + wave * 16;
    const int  b   = (int)(pb >> 12);
    const int  nnb = (int)(pb & 4095);

    half8 ax[2];
#pragma unroll
    for (int kh = 0; kh < 2; ++kh) {
        const float* xp = x + (p0 + n16) * 64 + kh * 32 + quad * 8;
        float4 x1 = *(const float4*)xp;
        float4 x2 = *(const float4*)(xp + 4);
        ax[kh][0] = (f16)x1.x; ax[kh][1] = (f16)x1.y;
        ax[kh][2] = (f16)x1.z; ax[kh][3] = (f16)x1.w;
        ax[kh][4] = (f16)x2.x; ax[kh][5] = (f16)x2.y;
        ax[kh][6] = (f16)x2.z; ax[kh][7] = (f16)x2.w;
    }

#pragma unroll
    for (int ct = 0; ct < 5; ++ct) {
        const int cout = (ct < 4) ? ct * 16 + n16 : 64 + n16;
        const float bias = Bs[cout];
        half8 b0 = *(const half8*)(&Ws[cout][quad * 8]);
        half8 b1 = *(const half8*)(&Ws[cout][32 + quad * 8]);
        floatx4 acc = {bias, bias, bias, bias};
        acc = __builtin_amdgcn_mfma_f32_16x16x32_f16(ax[0], b0, acc, 0, 0, 0);
        acc = __builtin_amdgcn_mfma_f32_16x16x32_f16(ax[1], b1, acc, 0, 0, 0);
        if (ct < 4) {
#pragma unroll
            for (int r = 0; r < 4; ++r)
                Vs[wave * 16 + quad * 4 + r][ct * 16 + n16] = (f16)acc[r];
        } else {
            float n2[4];
#pragma unroll
            for (int r = 0; r < 4; ++r) n2[r] = acc[r] * acc[r];
#pragma unroll
            for (int d = 1; d < 8; d <<= 1)
#pragma unroll
                for (int r = 0; r < 4; ++r) n2[r] += __shfl_xor(n2[r], d, 64);
            if (n16 == 0) {
#pragma unroll
                for (int r = 0; r < 4; ++r) qn2[p0 + quad * 4 + r] = n2[r];
            } else if (n16 == 8) {
#pragma unroll
                for (int r = 0; r < 4; ++r) kn2[p0 + quad * 4 + r] = n2[r];
            }
            if (n16 < 8) {
                f16* dst = Qh + (p0 + quad * 4) * 8 + n16;
#pragma unroll
                for (int r = 0; r < 4; ++r) dst[r * 8] = (f16)acc[r];
            } else {
#pragma unroll
                for (int r = 0; r < 4; ++r)
                    Ks[wave * 16 + quad * 4 + r][n16 - 8] = (f16)acc[r];
            }
        }
    }
    __syncthreads();

    // V fragment stores: 2 pairs x 4 ct = 8 tiles; 2 per wave, 16B/lane.
#pragma unroll
    for (int u = 0; u < 2; ++u) {
        const int tt = wave * 2 + u;
        const int p  = tt >> 2, ct = tt & 3;
        half8 v;
#pragma unroll
        for (int e = 0; e < 2; ++e)
#pragma unroll
            for (int j = 0; j < 4; ++j)
                v[e * 4 + j] = Vs[p * 32 + e * 16 + quad * 4 + j][ct * 16 + n16];
        const size_t pg = (size_t)b * 128 + (nnb >> 5) + p;
        *(half8*)(Vf + (pg * 4 + ct) * 512 + lane * 8) = v;
    }
    // K pair-tile stores: waves 0-1, full 16B/lane lines
    if (wave < 2) {
        half8 kp;
#pragma unroll
        for (int e = 0; e < 2; ++e) {
            const int t = wave * 2 + e;
#pragma unroll
            for (int j = 0; j < 4; ++j) {
                f16 v = (f16)0.f;
                if (quad < 2) v = Ks[t * 16 + n16][quad * 4 + j];
                else if (quad == 2 && j == 0) v = (f16)1.f;  // mf ones channel
                kp[e * 4 + j] = v;
            }
        }
        const size_t kpg = (size_t)b * 128 + (nnb >> 5) + wave;
        *(half8*)(Kf + kpg * 512 + lane * 8) = kp;
    }
}

// ---------------- per-batch max key-norm reduce ----------------
__global__ __launch_bounds__(256) void knorm_max_kernel(
    const float* __restrict__ kn2, float* __restrict__ Mk2)
{
    __shared__ float red[4];
    const int b = blockIdx.x, tid = threadIdx.x;
    float mx = 0.f;
    for (int i = tid; i < NN; i += 256) mx = fmaxf(mx, kn2[(size_t)b * NN + i]);
#pragma unroll
    for (int d = 1; d < 64; d <<= 1) mx = fmaxf(mx, __shfl_xor(mx, d, 64));
    if ((tid & 63) == 0) red[tid >> 6] = mx;
    __syncthreads();
    if (tid == 0) Mk2[b] = fmaxf(fmaxf(red[0], red[1]), fmaxf(red[2], red[3]));
}

// ---------------- flash attention, register-direct PV, 16 q/wave ----------------
// grid B*256 = 2048 x 256 thr; wave = ks (0..3): keys [ks*1024,+1024), 16 iters.
// launch_bounds(256,5): body needs 44 regs, cap 51 -> 5 blocks/CU.
__global__ __launch_bounds__(256, 5) void attn_kernel(
    const f16* __restrict__ Qh, const f16* __restrict__ Kf,
    const f16* __restrict__ Vf,
    const float* __restrict__ qn2, const float* __restrict__ Mk2,
    const float* __restrict__ x, const float* __restrict__ gptr,
    float* __restrict__ out)
{
    __shared__ alignas(16) float Obuf[3][64][16];   // 12.3 KB
    __shared__ float Ls[4][16];

    const int tid  = threadIdx.x;
    const int wave = tid >> 6, lane = tid & 63;
    const int quad = lane >> 4, n16 = lane & 15;
    const int ks = wave;

    const int b  = blockIdx.x & 7;
    const int qt = blockIdx.x >> 3;               // 0..255 (16-query tile)
    const int q  = qt * 16 + n16;
    const size_t bN = (size_t)b * NN;

    // Q B-frag: quads 0-1 = Q data; quad2 = {-mf,0,0,0}; quad3 = 0.
    const float mf = __builtin_sqrtf(qn2[bN + q] * Mk2[b]) - 12.0f;
    half4 bq4 = {0, 0, 0, 0};
    if (quad < 2)
        bq4 = *(const half4*)(Qh + (bN + q) * 8 + quad * 4);
    else if (quad == 2)
        bq4[0] = (f16)(-mf);

    floatx4 oacc[4];
#pragma unroll
    for (int ct = 0; ct < 4; ++ct) oacc[ct] = (floatx4){0.f, 0.f, 0.f, 0.f};
    float l_loc = 0.f;

    const f16* kfb = Kf + ((size_t)b * 128 + ks * 32) * 512;
    const f16* vfb = Vf + ((size_t)b * 128 + ks * 32) * 2048;
    const floatx4 zero4 = {0.f, 0.f, 0.f, 0.f};

    for (int it = 0; it < 16; ++it) {
        // K pair loads (2 x b128) + V pair loads (8 x b128), all coalesced
        half8 kk0 = *(const half8*)(kfb + (size_t)(it * 2 + 0) * 512 + lane * 8);
        half8 kk1 = *(const half8*)(kfb + (size_t)(it * 2 + 1) * 512 + lane * 8);
        half8 av[2][4];
#pragma unroll
        for (int qp = 0; qp < 2; ++qp)
#pragma unroll
            for (int ct = 0; ct < 4; ++ct)
                av[qp][ct] = *(const half8*)(vfb + ((size_t)(it * 2 + qp) * 4 + ct) * 512 + lane * 8);

        half4 ak[4];
        ak[0] = __builtin_shufflevector(kk0, kk0, 0, 1, 2, 3);
        ak[1] = __builtin_shufflevector(kk0, kk0, 4, 5, 6, 7);
        ak[2] = __builtin_shufflevector(kk1, kk1, 0, 1, 2, 3);
        ak[3] = __builtin_shufflevector(kk1, kk1, 4, 5, 6, 7);

        // S^T: D[key=quad*4+r (+16t)][query=n16], mf pre-subtracted via channel 8
        floatx4 sf[4];
#pragma unroll
        for (int t = 0; t < 4; ++t)
            sf[t] = __builtin_amdgcn_mfma_f32_16x16x16f16(ak[t], bq4, zero4, 0, 0, 0);

        // exp2 + pack: pk[t] IS the PV B-frag (D-layout == B-layout identity)
        float rst[4];
        half4 pk[4];
#pragma unroll
        for (int t = 0; t < 4; ++t) {
            float pv0 = __builtin_exp2f(sf[t][0]);
            float pv1 = __builtin_exp2f(sf[t][1]);
            float pv2 = __builtin_exp2f(sf[t][2]);
            float pv3 = __builtin_exp2f(sf[t][3]);
            rst[t] = (pv0 + pv1) + (pv2 + pv3);
            pk[t] = pack4(pv0, pv1, pv2, pv3);
        }
        l_loc += (rst[0] + rst[1]) + (rst[2] + rst[3]);

        // O^T += V^T P^T : 16 x 16x16x16 MFMAs, B straight from registers
#pragma unroll
        for (int t = 0; t < 4; ++t) {
            const int qp = t >> 1;
#pragma unroll
            for (int ct = 0; ct < 4; ++ct) {
                half4 va = (t & 1)
                    ? __builtin_shufflevector(av[qp][ct], av[qp][ct], 4, 5, 6, 7)
                    : __builtin_shufflevector(av[qp][ct], av[qp][ct], 0, 1, 2, 3);
                oacc[ct] = __builtin_amdgcn_mfma_f32_16x16x16f16(va, pk[t], oacc[ct], 0, 0, 0);
            }
        }
    }

    // fold per-lane l partials (lanes ^16,^32 share the query)
    float l_run = l_loc;
    l_run += __shfl_xor(l_run, 16, 64);
    l_run += __shfl_xor(l_run, 32, 64);

    __syncthreads();
    if (ks > 0) {
        if (quad == 0) Ls[ks][n16] = l_run;
        float* ob = &Obuf[ks - 1][lane][0];
#pragma unroll
        for (int ct = 0; ct < 4; ++ct)
            *(floatx4*)(ob + ct * 4) = oacc[ct];
    }
    __syncthreads();
    if (ks == 0) {
        float l = l_run;
        float o[16];
#pragma unroll
        for (int ct = 0; ct < 4; ++ct)
#pragma unroll
            for (int r = 0; r < 4; ++r) o[ct * 4 + r] = oacc[ct][r];
#pragma unroll
        for (int p = 1; p < 4; ++p) {
            l += Ls[p][n16];
            const float* ob = &Obuf[p - 1][lane][0];
#pragma unroll
            for (int i = 0; i < 16; ++i) o[i] += ob[i];
        }
        const float scale = gptr[0] / l;
#pragma unroll
        for (int ct = 0; ct < 4; ++ct) {
            const size_t idx = (bN + q) * CC + ct * 16 + quad * 4;
            float4 xr = *(const float4*)(x + idx);
            float4 res;
            res.x = o[ct * 4 + 0] * scale + xr.x;
            res.y = o[ct * 4 + 1] * scale + xr.y;
            res.z = o[ct * 4 + 2] * scale + xr.z;
            res.w = o[ct * 4 + 3] * scale + xr.w;
            *(float4*)(out + idx) = res;
        }
    }
}

extern "C" void kernel_launch(void* const* d_in, const int* in_sizes, int n_in,
                              void* d_out, int out_size, void* d_ws, size_t ws_size,
                              hipStream_t stream) {
    const float* x     = (const float*)d_in[0];
    const float* wq    = (const float*)d_in[1];
    const float* bq    = (const float*)d_in[2];
    const float* wk    = (const float*)d_in[3];
    const float* bk    = (const float*)d_in[4];
    const float* wv    = (const float*)d_in[5];
    const float* bv    = (const float*)d_in[6];
    const float* gamma = (const float*)d_in[7];
    float* out = (float*)d_out;

    // ws: Qh 512KB | Kf 1MB | Vf 4MB | qn2 128KB | kn2 128KB | Mk2 32B
    f16* Qh = (f16*)d_ws;
    f16* Kf = Qh + (size_t)BB * NN * 8;
    f16* Vf = Kf + (size_t)BB * 128 * 512;
    float* qn2 = (float*)(Vf + (size_t)BB * 128 * 4 * 512);
    float* kn2 = qn2 + (size_t)BB * NN;
    float* Mk2 = kn2 + (size_t)BB * NN;

    proj_all_kernel<<<512, 256, 0, stream>>>(x, wq, bq, wk, bk, wv, bv,
                                             Qh, Kf, Vf, qn2, kn2);
    knorm_max_kernel<<<BB, 256, 0, stream>>>(kn2, Mk2);
    attn_kernel<<<BB * 256, 256, 0, stream>>>(Qh, Kf, Vf, qn2, Mk2, x, gamma, out);
}

// Round 16
// 136.980 us; speedup vs baseline: 1.0093x; 1.0093x over previous
//
#include <hip/hip_runtime.h>
#include <hip/hip_bf16.h>

// ConvSelfAttn: B=8, N=4096, C=64, d=8. FP32 I/O.
// R16: 32 q/wave + register-direct PV (R13's V-amortization x R14's no-LDS).
// Grid 1024 x 256, key-split 4, launch_bounds(256,3). V/K loads shared by
// both q-subtiles -> V L2 traffic halves vs R14/R15. PV = 16x16x16 MFMAs with
// B straight from exp'd S registers (D-layout == B-layout identity). No Pbuf.
// Epilogue: R13-style Obuf merge (f32). Proj/knorm unchanged from R15.

#define BB 8
#define NN 4096
#define CC 64
#define PSTRIDE 72
#define LOG2E 1.44269504088896f

typedef _Float16 f16;
typedef _Float16 half8 __attribute__((ext_vector_type(8)));
typedef _Float16 half4 __attribute__((ext_vector_type(4)));
typedef __fp16 fp16x2 __attribute__((ext_vector_type(2)));
typedef float floatx4 __attribute__((ext_vector_type(4)));

static __device__ inline half4 pack4(float a, float b, float c, float d) {
    fp16x2 lo = __builtin_amdgcn_cvt_pkrtz(a, b);
    fp16x2 hi = __builtin_amdgcn_cvt_pkrtz(c, d);
    unsigned int lou = __builtin_bit_cast(unsigned int, lo);
    unsigned int hiu = __builtin_bit_cast(unsigned int, hi);
    unsigned long long packed = (unsigned long long)lou | ((unsigned long long)hiu << 32);
    return __builtin_bit_cast(half4, packed);
}

// ws layouts (halfs):
//   Qh [B*N][8]                     Q pre-scaled by log2e
//   Kf [B][128 pair][64 lane][8]    pair-interleaved S A-frags (16x16x16);
//                                   quad2 = {1,0,0,0} mf channel, quad3 = 0
//   Vf [B][128 pair][4 ct][64 lane][8]  pair-interleaved PV A-frags (16x16x16)
//   qn2 [B*N] f32 | kn2 [B*N] f32 | Mk2 [B] f32

// ---------------- fused projection + fragment repack + norms ----------------
__global__ __launch_bounds__(256) void proj_all_kernel(
    const float* __restrict__ x,
    const float* __restrict__ wq, const float* __restrict__ bq,
    const float* __restrict__ wk, const float* __restrict__ bk,
    const float* __restrict__ wv, const float* __restrict__ bv,
    f16* __restrict__ Qh, f16* __restrict__ Kf, f16* __restrict__ Vf,
    float* __restrict__ qn2, float* __restrict__ kn2)
{
    __shared__ alignas(16) f16 Ws[80][PSTRIDE];  // rows 0-63=V, 64-71=Q, 72-79=K
    __shared__ float Bs[80];
    __shared__ alignas(16) f16 Vs[64][68];       // [pixel][ch], pitch 68
    __shared__ alignas(16) f16 Ks[64][12];       // [pixel][ch]
    const int tid = threadIdx.x;

    for (int i = tid; i < 4096; i += 256) {
        int cin = i >> 6, cout = i & 63;
        Ws[cout][cin] = (f16)wv[i];
    }
    for (int i = tid; i < 512; i += 256) {
        int cin = i >> 3, c = i & 7;
        Ws[64 + c][cin] = (f16)(wq[i] * LOG2E);
        Ws[72 + c][cin] = (f16)wk[i];
    }
    if (tid < 80)
        Bs[tid] = (tid < 64) ? bv[tid]
                : (tid < 72 ? bq[tid - 64] * LOG2E : bk[tid - 72]);
    __syncthreads();

    const int wave = tid >> 6, lane = tid & 63;
    const int quad = lane >> 4, n16 = lane & 15;
    const long pb = (long)blockIdx.x * 64;
    const long p0 = pb + wave * 16;
    const int  b   = (int)(pb >> 12);
    const int  nnb = (int)(pb & 4095);

    half8 ax[2];
#pragma unroll
    for (int kh = 0; kh < 2; ++kh) {
        const float* xp = x + (p0 + n16) * 64 + kh * 32 + quad * 8;
        float4 x1 = *(const float4*)xp;
        float4 x2 = *(const float4*)(xp + 4);
        ax[kh][0] = (f16)x1.x; ax[kh][1] = (f16)x1.y;
        ax[kh][2] = (f16)x1.z; ax[kh][3] = (f16)x1.w;
        ax[kh][4] = (f16)x2.x; ax[kh][5] = (f16)x2.y;
        ax[kh][6] = (f16)x2.z; ax[kh][7] = (f16)x2.w;
    }

#pragma unroll
    for (int ct = 0; ct < 5; ++ct) {
        const int cout = (ct < 4) ? ct * 16 + n16 : 64 + n16;
        const float bias = Bs[cout];
        half8 b0 = *(const half8*)(&Ws[cout][quad * 8]);
        half8 b1 = *(const half8*)(&Ws[cout][32 + quad * 8]);
        floatx4 acc = {bias, bias, bias, bias};
        acc = __builtin_amdgcn_mfma_f32_16x16x32_f16(ax[0], b0, acc, 0, 0, 0);
        acc = __builtin_amdgcn_mfma_f32_16x16x32_f16(ax[1], b1, acc, 0, 0, 0);
        if (ct < 4) {
#pragma unroll
            for (int r = 0; r < 4; ++r)
                Vs[wave * 16 + quad * 4 + r][ct * 16 + n16] = (f16)acc[r];
        } else {
            float n2[4];
#pragma unroll
            for (int r = 0; r < 4; ++r) n2[r] = acc[r] * acc[r];
#pragma unroll
            for (int d = 1; d < 8; d <<= 1)
#pragma unroll
                for (int r = 0; r < 4; ++r) n2[r] += __shfl_xor(n2[r], d, 64);
            if (n16 == 0) {
#pragma unroll
                for (int r = 0; r < 4; ++r) qn2[p0 + quad * 4 + r] = n2[r];
            } else if (n16 == 8) {
#pragma unroll
                for (int r = 0; r < 4; ++r) kn2[p0 + quad * 4 + r] = n2[r];
            }
            if (n16 < 8) {
                f16* dst = Qh + (p0 + quad * 4) * 8 + n16;
#pragma unroll
                for (int r = 0; r < 4; ++r) dst[r * 8] = (f16)acc[r];
            } else {
#pragma unroll
                for (int r = 0; r < 4; ++r)
                    Ks[wave * 16 + quad * 4 + r][n16 - 8] = (f16)acc[r];
            }
        }
    }
    __syncthreads();

    // V fragment stores: 2 pairs x 4 ct = 8 tiles; 2 per wave, 16B/lane.
#pragma unroll
    for (int u = 0; u < 2; ++u) {
        const int tt = wave * 2 + u;
        const int p  = tt >> 2, ct = tt & 3;
        half8 v;
#pragma unroll
        for (int e = 0; e < 2; ++e)
#pragma unroll
            for (int j = 0; j < 4; ++j)
                v[e * 4 + j] = Vs[p * 32 + e * 16 + quad * 4 + j][ct * 16 + n16];
        const size_t pg = (size_t)b * 128 + (nnb >> 5) + p;
        *(half8*)(Vf + (pg * 4 + ct) * 512 + lane * 8) = v;
    }
    // K pair-tile stores: waves 0-1, full 16B/lane lines
    if (wave < 2) {
        half8 kp;
#pragma unroll
        for (int e = 0; e < 2; ++e) {
            const int t = wave * 2 + e;
#pragma unroll
            for (int j = 0; j < 4; ++j) {
                f16 v = (f16)0.f;
                if (quad < 2) v = Ks[t * 16 + n16][quad * 4 + j];
                else if (quad == 2 && j == 0) v = (f16)1.f;  // mf ones channel
                kp[e * 4 + j] = v;
            }
        }
        const size_t kpg = (size_t)b * 128 + (nnb >> 5) + wave;
        *(half8*)(Kf + kpg * 512 + lane * 8) = kp;
    }
}

// ---------------- per-batch max key-norm reduce ----------------
__global__ __launch_bounds__(256) void knorm_max_kernel(
    const float* __restrict__ kn2, float* __restrict__ Mk2)
{
    __shared__ float red[4];
    const int b = blockIdx.x, tid = threadIdx.x;
    float mx = 0.f;
    for (int i = tid; i < NN; i += 256) mx = fmaxf(mx, kn2[(size_t)b * NN + i]);
#pragma unroll
    for (int d = 1; d < 64; d <<= 1) mx = fmaxf(mx, __shfl_xor(mx, d, 64));
    if ((tid & 63) == 0) red[tid >> 6] = mx;
    __syncthreads();
    if (tid == 0) Mk2[b] = fmaxf(fmaxf(red[0], red[1]), fmaxf(red[2], red[3]));
}

// ---------------- flash attention, register-direct PV, 32 q/wave ----------------
// grid B*128 = 1024 x 256 thr; wave = ks (0..3): keys [ks*1024,+1024), 16 iters.
__global__ __launch_bounds__(256, 3) void attn_kernel(
    const f16* __restrict__ Qh, const f16* __restrict__ Kf,
    const f16* __restrict__ Vf,
    const float* __restrict__ qn2, const float* __restrict__ Mk2,
    const float* __restrict__ x, const float* __restrict__ gptr,
    float* __restrict__ out)
{
    __shared__ alignas(16) float Obuf[3][2][64][16];   // 24.6 KB
    __shared__ float Ls[4][2][16];

    const int tid  = threadIdx.x;
    const int wave = tid >> 6, lane = tid & 63;
    const int quad = lane >> 4, n16 = lane & 15;
    const int ks = wave;

    const int b  = blockIdx.x & 7;
    const int qt = blockIdx.x >> 3;               // 0..127 (32-query tile)
    const size_t bN = (size_t)b * NN;

    const float mk2 = Mk2[b];

    // Q B-frags: quads 0-1 = Q data; quad2 = {-mf,0,0,0}; quad3 = 0.
    half4 bq4[2];
#pragma unroll
    for (int qt2 = 0; qt2 < 2; ++qt2) {
        const int q = qt * 32 + qt2 * 16 + n16;
        const float mf = __builtin_sqrtf(qn2[bN + q] * mk2) - 12.0f;
        half4 v = {0, 0, 0, 0};
        if (quad < 2)
            v = *(const half4*)(Qh + (bN + q) * 8 + quad * 4);
        else if (quad == 2)
            v[0] = (f16)(-mf);
        bq4[qt2] = v;
    }

    floatx4 oacc[2][4];
#pragma unroll
    for (int qt2 = 0; qt2 < 2; ++qt2)
#pragma unroll
        for (int ct = 0; ct < 4; ++ct) oacc[qt2][ct] = (floatx4){0.f, 0.f, 0.f, 0.f};
    float l_loc[2] = {0.f, 0.f};

    const f16* kfb = Kf + ((size_t)b * 128 + ks * 32) * 512;
    const f16* vfb = Vf + ((size_t)b * 128 + ks * 32) * 2048;
    const floatx4 zero4 = {0.f, 0.f, 0.f, 0.f};

    for (int it = 0; it < 16; ++it) {
        // K pair loads (2 x b128) + V pair loads (8 x b128), all coalesced;
        // shared by both q-subtiles.
        half8 kk0 = *(const half8*)(kfb + (size_t)(it * 2 + 0) * 512 + lane * 8);
        half8 kk1 = *(const half8*)(kfb + (size_t)(it * 2 + 1) * 512 + lane * 8);
        half8 av[2][4];
#pragma unroll
        for (int qp = 0; qp < 2; ++qp)
#pragma unroll
            for (int ct = 0; ct < 4; ++ct)
                av[qp][ct] = *(const half8*)(vfb + ((size_t)(it * 2 + qp) * 4 + ct) * 512 + lane * 8);

        half4 ak[4];
        ak[0] = __builtin_shufflevector(kk0, kk0, 0, 1, 2, 3);
        ak[1] = __builtin_shufflevector(kk0, kk0, 4, 5, 6, 7);
        ak[2] = __builtin_shufflevector(kk1, kk1, 0, 1, 2, 3);
        ak[3] = __builtin_shufflevector(kk1, kk1, 4, 5, 6, 7);

#pragma unroll
        for (int qt2 = 0; qt2 < 2; ++qt2) {
            // S^T: D[key=quad*4+r (+16t)][query=n16], mf pre-subtracted
            floatx4 sf[4];
#pragma unroll
            for (int t = 0; t < 4; ++t)
                sf[t] = __builtin_amdgcn_mfma_f32_16x16x16f16(ak[t], bq4[qt2], zero4, 0, 0, 0);

            // exp2 + pack: pk[t] IS the PV B-frag (D-layout == B-layout)
            float rst[4];
            half4 pk[4];
#pragma unroll
            for (int t = 0; t < 4; ++t) {
                float pv0 = __builtin_exp2f(sf[t][0]);
                float pv1 = __builtin_exp2f(sf[t][1]);
                float pv2 = __builtin_exp2f(sf[t][2]);
                float pv3 = __builtin_exp2f(sf[t][3]);
                rst[t] = (pv0 + pv1) + (pv2 + pv3);
                pk[t] = pack4(pv0, pv1, pv2, pv3);
            }
            l_loc[qt2] += (rst[0] + rst[1]) + (rst[2] + rst[3]);

            // O^T += V^T P^T : 16 x 16x16x16 MFMAs, B straight from registers
#pragma unroll
            for (int t = 0; t < 4; ++t) {
                const int qp = t >> 1;
#pragma unroll
                for (int ct = 0; ct < 4; ++ct) {
                    half4 va = (t & 1)
                        ? __builtin_shufflevector(av[qp][ct], av[qp][ct], 4, 5, 6, 7)
                        : __builtin_shufflevector(av[qp][ct], av[qp][ct], 0, 1, 2, 3);
                    oacc[qt2][ct] = __builtin_amdgcn_mfma_f32_16x16x16f16(va, pk[t], oacc[qt2][ct], 0, 0, 0);
                }
            }
        }
    }

    // fold per-lane l partials (lanes ^16,^32 share the query)
    float l_run[2];
#pragma unroll
    for (int qt2 = 0; qt2 < 2; ++qt2) {
        float l = l_loc[qt2];
        l += __shfl_xor(l, 16, 64);
        l += __shfl_xor(l, 32, 64);
        l_run[qt2] = l;
    }

    __syncthreads();
    if (ks > 0) {
#pragma unroll
        for (int qt2 = 0; qt2 < 2; ++qt2) {
            if (quad == 0) Ls[ks][qt2][n16] = l_run[qt2];
            float* ob = &Obuf[ks - 1][qt2][lane][0];
#pragma unroll
            for (int ct = 0; ct < 4; ++ct)
                *(floatx4*)(ob + ct * 4) = oacc[qt2][ct];
        }
    }
    __syncthreads();
    if (ks == 0) {
        const float g = gptr[0];
#pragma unroll
        for (int qt2 = 0; qt2 < 2; ++qt2) {
            float l = l_run[qt2];
            float o[16];
#pragma unroll
            for (int ct = 0; ct < 4; ++ct)
#pragma unroll
                for (int r = 0; r < 4; ++r) o[ct * 4 + r] = oacc[qt2][ct][r];
#pragma unroll
            for (int p = 1; p < 4; ++p) {
                l += Ls[p][qt2][n16];
                const float* ob = &Obuf[p - 1][qt2][lane][0];
#pragma unroll
                for (int i = 0; i < 16; ++i) o[i] += ob[i];
            }
            const float scale = g / l;
            const int q = qt * 32 + qt2 * 16 + n16;
#pragma unroll
            for (int ct = 0; ct < 4; ++ct) {
                const size_t idx = (bN + q) * CC + ct * 16 + quad * 4;
                float4 xr = *(const float4*)(x + idx);
                float4 res;
                res.x = o[ct * 4 + 0] * scale + xr.x;
                res.y = o[ct * 4 + 1] * scale + xr.y;
                res.z = o[ct * 4 + 2] * scale + xr.z;
                res.w = o[ct * 4 + 3] * scale + xr.w;
                *(float4*)(out + idx) = res;
            }
        }
    }
}

extern "C" void kernel_launch(void* const* d_in, const int* in_sizes, int n_in,
                              void* d_out, int out_size, void* d_ws, size_t ws_size,
                              hipStream_t stream) {
    const float* x     = (const float*)d_in[0];
    const float* wq    = (const float*)d_in[1];
    const float* bq    = (const float*)d_in[2];
    const float* wk    = (const float*)d_in[3];
    const float* bk    = (const float*)d_in[4];
    const float* wv    = (const float*)d_in[5];
    const float* bv    = (const float*)d_in[6];
    const float* gamma = (const float*)d_in[7];
    float* out = (float*)d_out;

    // ws: Qh 512KB | Kf 1MB | Vf 4MB | qn2 128KB | kn2 128KB | Mk2 32B
    f16* Qh = (f16*)d_ws;
    f16* Kf = Qh + (size_t)BB * NN * 8;
    f16* Vf = Kf + (size_t)BB * 128 * 512;
    float* qn2 = (float*)(Vf + (size_t)BB * 128 * 4 * 512);
    float* kn2 = qn2 + (size_t)BB * NN;
    float* Mk2 = kn2 + (size_t)BB * NN;

    proj_all_kernel<<<512, 256, 0, stream>>>(x, wq, bq, wk, bk, wv, bv,
                                             Qh, Kf, Vf, qn2, kn2);
    knorm_max_kernel<<<BB, 256, 0, stream>>>(kn2, Mk2);
    attn_kernel<<<BB * 128, 256, 0, stream>>>(Qh, Kf, Vf, qn2, Mk2, x, gamma, out);
}

// Round 17
// 131.005 us; speedup vs baseline: 1.0554x; 1.0456x over previous
//
#include <hip/hip_runtime.h>
#include <hip/hip_bf16.h>

// ConvSelfAttn: B=8, N=4096, C=64, d=8. FP32 I/O.
// R17: R13 config (best total: 32 q/wave, K=32 PV, hoisted loads, (256,3),
// grid 1024) with the P LDS round-trip replaced by cross-lane shuffles:
// D-layout -> B(K=32)-layout is a quad permutation at fixed n16 ->
// 16 shfl + 8 cndmask per subtile (ds_bpermute, 2-way broadcast = conflict-
// free). No Pbuf, no lgkmcnt(0) drain. Proj/knorm = R13 verbatim.

#define BB 8
#define NN 4096
#define CC 64
#define PSTRIDE 72
#define LOG2E 1.44269504088896f

typedef _Float16 f16;
typedef _Float16 half8 __attribute__((ext_vector_type(8)));
typedef _Float16 half4 __attribute__((ext_vector_type(4)));
typedef __fp16 fp16x2 __attribute__((ext_vector_type(2)));
typedef float floatx4 __attribute__((ext_vector_type(4)));

static __device__ inline half4 pack4(float a, float b, float c, float d) {
    fp16x2 lo = __builtin_amdgcn_cvt_pkrtz(a, b);
    fp16x2 hi = __builtin_amdgcn_cvt_pkrtz(c, d);
    unsigned int lou = __builtin_bit_cast(unsigned int, lo);
    unsigned int hiu = __builtin_bit_cast(unsigned int, hi);
    unsigned long long packed = (unsigned long long)lou | ((unsigned long long)hiu << 32);
    return __builtin_bit_cast(half4, packed);
}

// D->B(K=32) exchange: dest (quad,n16) assembles B[k=quad*8+j][n16] from
// pk[pa]=tile 2g (dest quads 0,1) / pk[pb]=tile 2g+1 (dest quads 2,3), pulled
// from source lanes sA=((quad&1)*2)*16+n16 (j=0..3) and sB=sA+16 (j=4..7).
static __device__ inline half8 exch32(uint2 pa, uint2 pb, int sA, int sB, bool losel) {
    int a0 = __shfl((int)pa.x, sA, 64);
    int b0 = __shfl((int)pb.x, sA, 64);
    int a1 = __shfl((int)pa.y, sA, 64);
    int b1 = __shfl((int)pb.y, sA, 64);
    int a2 = __shfl((int)pa.x, sB, 64);
    int b2 = __shfl((int)pb.x, sB, 64);
    int a3 = __shfl((int)pa.y, sB, 64);
    int b3 = __shfl((int)pb.y, sB, 64);
    uint4 r;
    r.x = (unsigned)(losel ? a0 : b0);
    r.y = (unsigned)(losel ? a1 : b1);
    r.z = (unsigned)(losel ? a2 : b2);
    r.w = (unsigned)(losel ? a3 : b3);
    return __builtin_bit_cast(half8, r);
}

// ws layouts (halfs):
//   Qh [B*N][8]                     Q pre-scaled by log2e
//   Kf [B][128 pair][64 lane][8]    pair-interleaved S A-frags (16x16x16);
//                                   quad2 = {1,0,0,0} mf channel, quad3 = 0
//   Vf [B][128 kb32][4 ct][64 lane][8]  K=32 PV A-frags: A[m=ch][k=quad*8+j]
//   qn2 [B*N] f32 | kn2 [B*N] f32 | Mk2 [B] f32

// ---------------- fused projection + fragment repack + norms ----------------
__global__ __launch_bounds__(256) void proj_all_kernel(
    const float* __restrict__ x,
    const float* __restrict__ wq, const float* __restrict__ bq,
    const float* __restrict__ wk, const float* __restrict__ bk,
    const float* __restrict__ wv, const float* __restrict__ bv,
    f16* __restrict__ Qh, f16* __restrict__ Kf, f16* __restrict__ Vf,
    float* __restrict__ qn2, float* __restrict__ kn2)
{
    __shared__ alignas(16) f16 Ws[80][PSTRIDE];  // rows 0-63=V, 64-71=Q, 72-79=K
    __shared__ float Bs[80];
    __shared__ alignas(16) f16 Vs[64][68];       // [pixel][ch], pitch 68
    __shared__ alignas(16) f16 Ks[64][12];       // [pixel][ch]
    const int tid = threadIdx.x;

    for (int i = tid; i < 4096; i += 256) {
        int cin = i >> 6, cout = i & 63;
        Ws[cout][cin] = (f16)wv[i];
    }
    for (int i = tid; i < 512; i += 256) {
        int cin = i >> 3, c = i & 7;
        Ws[64 + c][cin] = (f16)(wq[i] * LOG2E);
        Ws[72 + c][cin] = (f16)wk[i];
    }
    if (tid < 80)
        Bs[tid] = (tid < 64) ? bv[tid]
                : (tid < 72 ? bq[tid - 64] * LOG2E : bk[tid - 72]);
    __syncthreads();

    const int wave = tid >> 6, lane = tid & 63;
    const int quad = lane >> 4, n16 = lane & 15;
    const long pb = (long)blockIdx.x * 64;
    const long p0 = pb + wave * 16;
    const int  b   = (int)(pb >> 12);
    const int  nnb = (int)(pb & 4095);

    half8 ax[2];
#pragma unroll
    for (int kh = 0; kh < 2; ++kh) {
        const float* xp = x + (p0 + n16) * 64 + kh * 32 + quad * 8;
        float4 x1 = *(const float4*)xp;
        float4 x2 = *(const float4*)(xp + 4);
        ax[kh][0] = (f16)x1.x; ax[kh][1] = (f16)x1.y;
        ax[kh][2] = (f16)x1.z; ax[kh][3] = (f16)x1.w;
        ax[kh][4] = (f16)x2.x; ax[kh][5] = (f16)x2.y;
        ax[kh][6] = (f16)x2.z; ax[kh][7] = (f16)x2.w;
    }

#pragma unroll
    for (int ct = 0; ct < 5; ++ct) {
        const int cout = (ct < 4) ? ct * 16 + n16 : 64 + n16;
        const float bias = Bs[cout];
        half8 b0 = *(const half8*)(&Ws[cout][quad * 8]);
        half8 b1 = *(const half8*)(&Ws[cout][32 + quad * 8]);
        floatx4 acc = {bias, bias, bias, bias};
        acc = __builtin_amdgcn_mfma_f32_16x16x32_f16(ax[0], b0, acc, 0, 0, 0);
        acc = __builtin_amdgcn_mfma_f32_16x16x32_f16(ax[1], b1, acc, 0, 0, 0);
        if (ct < 4) {
#pragma unroll
            for (int r = 0; r < 4; ++r)
                Vs[wave * 16 + quad * 4 + r][ct * 16 + n16] = (f16)acc[r];
        } else {
            float n2[4];
#pragma unroll
            for (int r = 0; r < 4; ++r) n2[r] = acc[r] * acc[r];
#pragma unroll
            for (int d = 1; d < 8; d <<= 1)
#pragma unroll
                for (int r = 0; r < 4; ++r) n2[r] += __shfl_xor(n2[r], d, 64);
            if (n16 == 0) {
#pragma unroll
                for (int r = 0; r < 4; ++r) qn2[p0 + quad * 4 + r] = n2[r];
            } else if (n16 == 8) {
#pragma unroll
                for (int r = 0; r < 4; ++r) kn2[p0 + quad * 4 + r] = n2[r];
            }
            if (n16 < 8) {
                f16* dst = Qh + (p0 + quad * 4) * 8 + n16;
#pragma unroll
                for (int r = 0; r < 4; ++r) dst[r * 8] = (f16)acc[r];
            } else {
#pragma unroll
                for (int r = 0; r < 4; ++r)
                    Ks[wave * 16 + quad * 4 + r][n16 - 8] = (f16)acc[r];
            }
        }
    }
    __syncthreads();

    // V fragment stores (K=32 A-frags): 2 kb x 4 ct = 8 tiles; 2 per wave.
#pragma unroll
    for (int u = 0; u < 2; ++u) {
        const int tt = wave * 2 + u;
        const int kb = tt >> 2, ct = tt & 3;
        half8 v;
#pragma unroll
        for (int j = 0; j < 8; ++j)
            v[j] = Vs[kb * 32 + quad * 8 + j][ct * 16 + n16];
        const size_t kbg = (size_t)b * 128 + (nnb >> 5) + kb;
        *(half8*)(Vf + (kbg * 4 + ct) * 512 + lane * 8) = v;
    }
    // K pair-tile stores: waves 0-1, full 16B/lane lines
    if (wave < 2) {
        half8 kp;
#pragma unroll
        for (int e = 0; e < 2; ++e) {
            const int t = wave * 2 + e;
#pragma unroll
            for (int j = 0; j < 4; ++j) {
                f16 v = (f16)0.f;
                if (quad < 2) v = Ks[t * 16 + n16][quad * 4 + j];
                else if (quad == 2 && j == 0) v = (f16)1.f;  // mf ones channel
                kp[e * 4 + j] = v;
            }
        }
        const size_t kpg = (size_t)b * 128 + (nnb >> 5) + wave;
        *(half8*)(Kf + kpg * 512 + lane * 8) = kp;
    }
}

// ---------------- per-batch max key-norm reduce ----------------
__global__ __launch_bounds__(256) void knorm_max_kernel(
    const float* __restrict__ kn2, float* __restrict__ Mk2)
{
    __shared__ float red[4];
    const int b = blockIdx.x, tid = threadIdx.x;
    float mx = 0.f;
    for (int i = tid; i < NN; i += 256) mx = fmaxf(mx, kn2[(size_t)b * NN + i]);
#pragma unroll
    for (int d = 1; d < 64; d <<= 1) mx = fmaxf(mx, __shfl_xor(mx, d, 64));
    if ((tid & 63) == 0) red[tid >> 6] = mx;
    __syncthreads();
    if (tid == 0) Mk2[b] = fmaxf(fmaxf(red[0], red[1]), fmaxf(red[2], red[3]));
}

// ---------------- flash attention, shfl P-transform, 32 q/wave ----------------
// grid B*128 = 1024 x 256 thr; wave = ks (0..3): keys [ks*1024,+1024), 16 iters.
__global__ __launch_bounds__(256, 3) void attn_kernel(
    const f16* __restrict__ Qh, const f16* __restrict__ Kf,
    const f16* __restrict__ Vf,
    const float* __restrict__ qn2, const float* __restrict__ Mk2,
    const float* __restrict__ x, const float* __restrict__ gptr,
    float* __restrict__ out)
{
    __shared__ alignas(16) float Obuf[3][2][64][16];   // 24.6 KB
    __shared__ float Ls[4][2][16];

    const int tid  = threadIdx.x;
    const int wave = tid >> 6, lane = tid & 63;
    const int quad = lane >> 4, n16 = lane & 15;
    const int ks = wave;

    const int b  = blockIdx.x & 7;
    const int qt = blockIdx.x >> 3;               // 0..127 (32-query tile)
    const size_t bN = (size_t)b * NN;

    const float mk2 = Mk2[b];
    const int sA = (quad & 1) * 32 + n16;         // exchange source lanes
    const int sB = sA + 16;
    const bool losel = quad < 2;

    // Q B-frags: quads 0-1 = Q data; quad2 = {-mf,0,0,0}; quad3 = 0.
    half4 bq4[2];
#pragma unroll
    for (int qt2 = 0; qt2 < 2; ++qt2) {
        const int q = qt * 32 + qt2 * 16 + n16;
        const float mf = __builtin_sqrtf(qn2[bN + q] * mk2) - 12.0f;
        half4 v = {0, 0, 0, 0};
        if (quad < 2)
            v = *(const half4*)(Qh + (bN + q) * 8 + quad * 4);
        else if (quad == 2)
            v[0] = (f16)(-mf);
        bq4[qt2] = v;
    }

    floatx4 oacc[2][4];
#pragma unroll
    for (int qt2 = 0; qt2 < 2; ++qt2)
#pragma unroll
        for (int ct = 0; ct < 4; ++ct) oacc[qt2][ct] = (floatx4){0.f, 0.f, 0.f, 0.f};
    float l_loc[2] = {0.f, 0.f};

    const f16* kfb = Kf + ((size_t)b * 128 + ks * 32) * 512;
    const f16* vfb = Vf + ((size_t)b * 128 + ks * 32) * 2048;
    const floatx4 zero4 = {0.f, 0.f, 0.f, 0.f};

    for (int it = 0; it < 16; ++it) {
        // all 10 global loads hoisted (K pair x2 + V kb x2 x ct x4), coalesced
        half8 kk0 = *(const half8*)(kfb + (size_t)(it * 2 + 0) * 512 + lane * 8);
        half8 kk1 = *(const half8*)(kfb + (size_t)(it * 2 + 1) * 512 + lane * 8);
        half8 av0[4], av1[4];
#pragma unroll
        for (int ct = 0; ct < 4; ++ct)
            av0[ct] = *(const half8*)(vfb + ((size_t)(it * 2) * 4 + ct) * 512 + lane * 8);
#pragma unroll
        for (int ct = 0; ct < 4; ++ct)
            av1[ct] = *(const half8*)(vfb + ((size_t)(it * 2 + 1) * 4 + ct) * 512 + lane * 8);

        half4 ak[4];
        ak[0] = __builtin_shufflevector(kk0, kk0, 0, 1, 2, 3);
        ak[1] = __builtin_shufflevector(kk0, kk0, 4, 5, 6, 7);
        ak[2] = __builtin_shufflevector(kk1, kk1, 0, 1, 2, 3);
        ak[3] = __builtin_shufflevector(kk1, kk1, 4, 5, 6, 7);

#pragma unroll
        for (int qt2 = 0; qt2 < 2; ++qt2) {
            // S^T: D[key=quad*4+r (+16t)][query=n16], mf pre-subtracted
            floatx4 sf[4];
#pragma unroll
            for (int t = 0; t < 4; ++t)
                sf[t] = __builtin_amdgcn_mfma_f32_16x16x16f16(ak[t], bq4[qt2], zero4, 0, 0, 0);

            // exp2 + pack per 16-key tile
            float rst[4];
            uint2 pk[4];
#pragma unroll
            for (int t = 0; t < 4; ++t) {
                float pv0 = __builtin_exp2f(sf[t][0]);
                float pv1 = __builtin_exp2f(sf[t][1]);
                float pv2 = __builtin_exp2f(sf[t][2]);
                float pv3 = __builtin_exp2f(sf[t][3]);
                rst[t] = (pv0 + pv1) + (pv2 + pv3);
                pk[t] = __builtin_bit_cast(uint2, pack4(pv0, pv1, pv2, pv3));
            }
            l_loc[qt2] += (rst[0] + rst[1]) + (rst[2] + rst[3]);

            // D -> B(K=32) via shuffles; then 8 K=32 PV MFMAs
            half8 bp0 = exch32(pk[0], pk[1], sA, sB, losel);
            half8 bp1 = exch32(pk[2], pk[3], sA, sB, losel);
#pragma unroll
            for (int ct = 0; ct < 4; ++ct)
                oacc[qt2][ct] = __builtin_amdgcn_mfma_f32_16x16x32_f16(av0[ct], bp0, oacc[qt2][ct], 0, 0, 0);
#pragma unroll
            for (int ct = 0; ct < 4; ++ct)
                oacc[qt2][ct] = __builtin_amdgcn_mfma_f32_16x16x32_f16(av1[ct], bp1, oacc[qt2][ct], 0, 0, 0);
        }
    }

    // fold per-lane l partials (lanes ^16,^32 share the query)
    float l_run[2];
#pragma unroll
    for (int qt2 = 0; qt2 < 2; ++qt2) {
        float l = l_loc[qt2];
        l += __shfl_xor(l, 16, 64);
        l += __shfl_xor(l, 32, 64);
        l_run[qt2] = l;
    }

    __syncthreads();
    if (ks > 0) {
#pragma unroll
        for (int qt2 = 0; qt2 < 2; ++qt2) {
            if (quad == 0) Ls[ks][qt2][n16] = l_run[qt2];
            float* ob = &Obuf[ks - 1][qt2][lane][0];
#pragma unroll
            for (int ct = 0; ct < 4; ++ct)
                *(floatx4*)(ob + ct * 4) = oacc[qt2][ct];
        }
    }
    __syncthreads();
    if (ks == 0) {
        const float g = gptr[0];
#pragma unroll
        for (int qt2 = 0; qt2 < 2; ++qt2) {
            float l = l_run[qt2];
            float o[16];
#pragma unroll
            for (int ct = 0; ct < 4; ++ct)
#pragma unroll
                for (int r = 0; r < 4; ++r) o[ct * 4 + r] = oacc[qt2][ct][r];
#pragma unroll
            for (int p = 1; p < 4; ++p) {
                l += Ls[p][qt2][n16];
                const float* ob = &Obuf[p - 1][qt2][lane][0];
#pragma unroll
                for (int i = 0; i < 16; ++i) o[i] += ob[i];
            }
            const float scale = g / l;
            const int q = qt * 32 + qt2 * 16 + n16;
#pragma unroll
            for (int ct = 0; ct < 4; ++ct) {
                const size_t idx = (bN + q) * CC + ct * 16 + quad * 4;
                float4 xr = *(const float4*)(x + idx);
                float4 res;
                res.x = o[ct * 4 + 0] * scale + xr.x;
                res.y = o[ct * 4 + 1] * scale + xr.y;
                res.z = o[ct * 4 + 2] * scale + xr.z;
                res.w = o[ct * 4 + 3] * scale + xr.w;
                *(float4*)(out + idx) = res;
            }
        }
    }
}

extern "C" void kernel_launch(void* const* d_in, const int* in_sizes, int n_in,
                              void* d_out, int out_size, void* d_ws, size_t ws_size,
                              hipStream_t stream) {
    const float* x     = (const float*)d_in[0];
    const float* wq    = (const float*)d_in[1];
    const float* bq    = (const float*)d_in[2];
    const float* wk    = (const float*)d_in[3];
    const float* bk    = (const float*)d_in[4];
    const float* wv    = (const float*)d_in[5];
    const float* bv    = (const float*)d_in[6];
    const float* gamma = (const float*)d_in[7];
    float* out = (float*)d_out;

    // ws: Qh 512KB | Kf 1MB | Vf 4MB | qn2 128KB | kn2 128KB | Mk2 32B
    f16* Qh = (f16*)d_ws;
    f16* Kf = Qh + (size_t)BB * NN * 8;
    f16* Vf = Kf + (size_t)BB * 128 * 512;
    float* qn2 = (float*)(Vf + (size_t)BB * 128 * 4 * 512);
    float* kn2 = qn2 + (size_t)BB * NN;
    float* Mk2 = kn2 + (size_t)BB * NN;

    proj_all_kernel<<<512, 256, 0, stream>>>(x, wq, bq, wk, bk, wv, bv,
                                             Qh, Kf, Vf, qn2, kn2);
    knorm_max_kernel<<<BB, 256, 0, stream>>>(kn2, Mk2);
    attn_kernel<<<BB * 128, 256, 0, stream>>>(Qh, Kf, Vf, qn2, Mk2, x, gamma, out);
}